// Round 1
// baseline (114.656 us; speedup 1.0000x reference)
//
#include <hip/hip_runtime.h>

#define NUM_CLASSES 32
#define NBINS (NUM_CLASSES * NUM_CLASSES)
#define BLOCK 256
#define GRID 1024

__global__ __launch_bounds__(BLOCK) void confmat_kernel(
    const int* __restrict__ y_true,
    const int* __restrict__ y_pred,
    float* __restrict__ out,
    int n)
{
    __shared__ unsigned int hist[NBINS];
    #pragma unroll
    for (int i = threadIdx.x; i < NBINS; i += BLOCK) hist[i] = 0u;
    __syncthreads();

    const int tid    = blockIdx.x * BLOCK + threadIdx.x;
    const int stride = GRID * BLOCK;

    // Vectorized main body: int4 loads of both arrays (16 B/lane each).
    const int n4 = n >> 2;  // number of int4 chunks
    const int4* __restrict__ t4 = (const int4*)y_true;
    const int4* __restrict__ p4 = (const int4*)y_pred;
    for (int i = tid; i < n4; i += stride) {
        int4 a = t4[i];
        int4 b = p4[i];
        if (a.x != 0) atomicAdd(&hist[a.x * NUM_CLASSES + b.x], 1u);
        if (a.y != 0) atomicAdd(&hist[a.y * NUM_CLASSES + b.y], 1u);
        if (a.z != 0) atomicAdd(&hist[a.z * NUM_CLASSES + b.z], 1u);
        if (a.w != 0) atomicAdd(&hist[a.w * NUM_CLASSES + b.w], 1u);
    }

    // Scalar tail (n not divisible by 4).
    for (int i = (n4 << 2) + tid; i < n; i += stride) {
        int a = y_true[i];
        int b = y_pred[i];
        if (a != 0) atomicAdd(&hist[a * NUM_CLASSES + b], 1u);
    }

    __syncthreads();

    // Flush block-private histogram: one global atomic per nonzero bin.
    // Counts are integers < 2^24 so float accumulation is exact.
    #pragma unroll
    for (int i = threadIdx.x; i < NBINS; i += BLOCK) {
        unsigned int c = hist[i];
        if (c) atomicAdd(&out[i], (float)c);
    }
}

extern "C" void kernel_launch(void* const* d_in, const int* in_sizes, int n_in,
                              void* d_out, int out_size, void* d_ws, size_t ws_size,
                              hipStream_t stream) {
    const int* y_true = (const int*)d_in[0];
    const int* y_pred = (const int*)d_in[1];
    float* out = (float*)d_out;
    int n = in_sizes[0];

    // d_out is poisoned 0xAA before every timed call — zero it on-stream.
    hipMemsetAsync(out, 0, (size_t)out_size * sizeof(float), stream);

    confmat_kernel<<<GRID, BLOCK, 0, stream>>>(y_true, y_pred, out, n);
}

// Round 2
// 101.999 us; speedup vs baseline: 1.1241x; 1.1241x over previous
//
#include <hip/hip_runtime.h>

#define NUM_CLASSES 32
#define NBINS (NUM_CLASSES * NUM_CLASSES)   // 1024
#define BLOCK 256
#define GRID1 2048                          // 8 blocks/CU resident -> 32 waves/CU
#define GRID2 64                            // reduce kernel blocks

// Stage 1: per-block private LDS histogram, flushed to ws (no global atomics).
__global__ __launch_bounds__(BLOCK) void confmat_partial(
    const int* __restrict__ y_true,
    const int* __restrict__ y_pred,
    unsigned int* __restrict__ ws,   // GRID1 x NBINS partial histograms
    int n)
{
    __shared__ unsigned int hist[NBINS];
    #pragma unroll
    for (int i = threadIdx.x; i < NBINS; i += BLOCK) hist[i] = 0u;
    __syncthreads();

    const int tid    = blockIdx.x * BLOCK + threadIdx.x;
    const int stride = GRID1 * BLOCK;
    const int n4 = n >> 2;
    const int4* __restrict__ t4 = (const int4*)y_true;
    const int4* __restrict__ p4 = (const int4*)y_pred;

    int i = tid;
    // Fast path: 8 independent int4 loads in flight before any LDS op.
    // For n = 8M this covers every element in exactly one iteration.
    for (; i + 3 * stride < n4; i += 4 * stride) {
        int4 a0 = t4[i];              int4 b0 = p4[i];
        int4 a1 = t4[i + stride];     int4 b1 = p4[i + stride];
        int4 a2 = t4[i + 2 * stride]; int4 b2 = p4[i + 2 * stride];
        int4 a3 = t4[i + 3 * stride]; int4 b3 = p4[i + 3 * stride];
        if (a0.x) atomicAdd(&hist[a0.x * NUM_CLASSES + b0.x], 1u);
        if (a0.y) atomicAdd(&hist[a0.y * NUM_CLASSES + b0.y], 1u);
        if (a0.z) atomicAdd(&hist[a0.z * NUM_CLASSES + b0.z], 1u);
        if (a0.w) atomicAdd(&hist[a0.w * NUM_CLASSES + b0.w], 1u);
        if (a1.x) atomicAdd(&hist[a1.x * NUM_CLASSES + b1.x], 1u);
        if (a1.y) atomicAdd(&hist[a1.y * NUM_CLASSES + b1.y], 1u);
        if (a1.z) atomicAdd(&hist[a1.z * NUM_CLASSES + b1.z], 1u);
        if (a1.w) atomicAdd(&hist[a1.w * NUM_CLASSES + b1.w], 1u);
        if (a2.x) atomicAdd(&hist[a2.x * NUM_CLASSES + b2.x], 1u);
        if (a2.y) atomicAdd(&hist[a2.y * NUM_CLASSES + b2.y], 1u);
        if (a2.z) atomicAdd(&hist[a2.z * NUM_CLASSES + b2.z], 1u);
        if (a2.w) atomicAdd(&hist[a2.w * NUM_CLASSES + b2.w], 1u);
        if (a3.x) atomicAdd(&hist[a3.x * NUM_CLASSES + b3.x], 1u);
        if (a3.y) atomicAdd(&hist[a3.y * NUM_CLASSES + b3.y], 1u);
        if (a3.z) atomicAdd(&hist[a3.z * NUM_CLASSES + b3.z], 1u);
        if (a3.w) atomicAdd(&hist[a3.w * NUM_CLASSES + b3.w], 1u);
    }
    for (; i < n4; i += stride) {
        int4 a = t4[i]; int4 b = p4[i];
        if (a.x) atomicAdd(&hist[a.x * NUM_CLASSES + b.x], 1u);
        if (a.y) atomicAdd(&hist[a.y * NUM_CLASSES + b.y], 1u);
        if (a.z) atomicAdd(&hist[a.z * NUM_CLASSES + b.z], 1u);
        if (a.w) atomicAdd(&hist[a.w * NUM_CLASSES + b.w], 1u);
    }
    // Scalar tail (n not divisible by 4).
    for (int j = (n4 << 2) + tid; j < n; j += stride) {
        int a = y_true[j]; int b = y_pred[j];
        if (a) atomicAdd(&hist[a * NUM_CLASSES + b], 1u);
    }

    __syncthreads();

    // Flush: plain coalesced uint4 stores, 4 KB per block, no atomics.
    uint4* __restrict__ w4 = (uint4*)(ws + (size_t)blockIdx.x * NBINS);
    const uint4* __restrict__ h4 = (const uint4*)hist;
    w4[threadIdx.x] = h4[threadIdx.x];
}

// Stage 2: column-sum the GRID1 partial histograms. Each block handles
// GRID1/GRID2 partials; thread t accumulates bins [4t, 4t+4) via uint4
// loads (fully coalesced, 16 B/lane). 64 atomics per out address total.
__global__ __launch_bounds__(BLOCK) void confmat_reduce(
    const unsigned int* __restrict__ ws,
    float* __restrict__ out)
{
    const int t = threadIdx.x;                 // 256 threads = 256 uint4 bins
    const int pbase = blockIdx.x * (GRID1 / GRID2);
    const uint4* __restrict__ w4 = (const uint4*)ws;
    unsigned int sx = 0, sy = 0, sz = 0, sw = 0;
    #pragma unroll 8
    for (int p = 0; p < GRID1 / GRID2; ++p) {
        uint4 v = w4[(size_t)(pbase + p) * (NBINS / 4) + t];
        sx += v.x; sy += v.y; sz += v.z; sw += v.w;
    }
    atomicAdd(&out[4 * t + 0], (float)sx);
    atomicAdd(&out[4 * t + 1], (float)sy);
    atomicAdd(&out[4 * t + 2], (float)sz);
    atomicAdd(&out[4 * t + 3], (float)sw);
}

extern "C" void kernel_launch(void* const* d_in, const int* in_sizes, int n_in,
                              void* d_out, int out_size, void* d_ws, size_t ws_size,
                              hipStream_t stream) {
    const int* y_true = (const int*)d_in[0];
    const int* y_pred = (const int*)d_in[1];
    float* out = (float*)d_out;
    unsigned int* ws = (unsigned int*)d_ws;    // needs GRID1*NBINS*4 = 8 MB
    int n = in_sizes[0];

    // d_out is poisoned 0xAA before every timed call — zero it on-stream.
    hipMemsetAsync(out, 0, (size_t)out_size * sizeof(float), stream);

    confmat_partial<<<GRID1, BLOCK, 0, stream>>>(y_true, y_pred, ws, n);
    confmat_reduce<<<GRID2, BLOCK, 0, stream>>>(ws, out);
}

// Round 3
// 101.157 us; speedup vs baseline: 1.1334x; 1.0083x over previous
//
#include <hip/hip_runtime.h>

#define NUM_CLASSES 32
#define NBINS (NUM_CLASSES * NUM_CLASSES)   // 1024
#define BLOCK 256
#define GRID1 2048                          // 8 blocks/CU resident -> 32 waves/CU
#define GRID2 NUM_CLASSES                   // one block per output row

// Stage 1: per-block private LDS histogram, flushed to ws (no global atomics).
// Counts ALL pixels unconditionally (bin = yt*32+yp is always in [0,1024));
// the yt==0 mask is applied in stage 2 by zeroing row 0 (reference: w=0 there).
__global__ __launch_bounds__(BLOCK) void confmat_partial(
    const int* __restrict__ y_true,
    const int* __restrict__ y_pred,
    unsigned int* __restrict__ ws,   // GRID1 x NBINS partial histograms
    int n)
{
    __shared__ unsigned int hist[NBINS];
    #pragma unroll
    for (int i = threadIdx.x; i < NBINS; i += BLOCK) hist[i] = 0u;
    __syncthreads();

    const int tid    = blockIdx.x * BLOCK + threadIdx.x;
    const int stride = GRID1 * BLOCK;
    const int n4 = n >> 2;
    const int4* __restrict__ t4 = (const int4*)y_true;
    const int4* __restrict__ p4 = (const int4*)y_pred;

    int i = tid;
    // 8 independent int4 loads in flight before any LDS op. For n = 8M this
    // covers every element in exactly one iteration (16 elems/thread).
    for (; i + 3 * stride < n4; i += 4 * stride) {
        int4 a0 = t4[i];              int4 b0 = p4[i];
        int4 a1 = t4[i + stride];     int4 b1 = p4[i + stride];
        int4 a2 = t4[i + 2 * stride]; int4 b2 = p4[i + 2 * stride];
        int4 a3 = t4[i + 3 * stride]; int4 b3 = p4[i + 3 * stride];
        atomicAdd(&hist[(a0.x << 5) | b0.x], 1u);
        atomicAdd(&hist[(a0.y << 5) | b0.y], 1u);
        atomicAdd(&hist[(a0.z << 5) | b0.z], 1u);
        atomicAdd(&hist[(a0.w << 5) | b0.w], 1u);
        atomicAdd(&hist[(a1.x << 5) | b1.x], 1u);
        atomicAdd(&hist[(a1.y << 5) | b1.y], 1u);
        atomicAdd(&hist[(a1.z << 5) | b1.z], 1u);
        atomicAdd(&hist[(a1.w << 5) | b1.w], 1u);
        atomicAdd(&hist[(a2.x << 5) | b2.x], 1u);
        atomicAdd(&hist[(a2.y << 5) | b2.y], 1u);
        atomicAdd(&hist[(a2.z << 5) | b2.z], 1u);
        atomicAdd(&hist[(a2.w << 5) | b2.w], 1u);
        atomicAdd(&hist[(a3.x << 5) | b3.x], 1u);
        atomicAdd(&hist[(a3.y << 5) | b3.y], 1u);
        atomicAdd(&hist[(a3.z << 5) | b3.z], 1u);
        atomicAdd(&hist[(a3.w << 5) | b3.w], 1u);
    }
    for (; i < n4; i += stride) {
        int4 a = t4[i]; int4 b = p4[i];
        atomicAdd(&hist[(a.x << 5) | b.x], 1u);
        atomicAdd(&hist[(a.y << 5) | b.y], 1u);
        atomicAdd(&hist[(a.z << 5) | b.z], 1u);
        atomicAdd(&hist[(a.w << 5) | b.w], 1u);
    }
    // Scalar tail (n not divisible by 4).
    for (int j = (n4 << 2) + tid; j < n; j += stride) {
        atomicAdd(&hist[(y_true[j] << 5) | y_pred[j]], 1u);
    }

    __syncthreads();

    // Flush: plain coalesced uint4 stores, 4 KB per block, no atomics.
    uint4* __restrict__ w4 = (uint4*)(ws + (size_t)blockIdx.x * NBINS);
    const uint4* __restrict__ h4 = (const uint4*)hist;
    w4[threadIdx.x] = h4[threadIdx.x];
}

// Stage 2: block b sums row b (32 bins) across all GRID1 partials and writes
// it with plain stores. Block 0 writes zeros (the yt==0 mask). No memset, no
// global atomics anywhere.
__global__ __launch_bounds__(BLOCK) void confmat_reduce(
    const unsigned int* __restrict__ ws,
    float* __restrict__ out)
{
    __shared__ unsigned int sums[NUM_CLASSES];
    if (threadIdx.x < NUM_CLASSES) sums[threadIdx.x] = 0u;
    __syncthreads();

    // Thread t: q = uint4-column within the row (8 per row), c = partial-chunk.
    const int q = threadIdx.x & 7;            // 0..7  (4 bins each)
    const int c = threadIdx.x >> 3;           // 0..31 (chunk of partials)
    const int row4 = blockIdx.x * (NUM_CLASSES / 4);  // uint4 index of row start
    const uint4* __restrict__ w4 = (const uint4*)ws;

    unsigned int sx = 0, sy = 0, sz = 0, sw = 0;
    const int chunk = GRID1 / 32;             // 64 partials per chunk
    #pragma unroll 8
    for (int k = 0; k < chunk; ++k) {
        int p = c * chunk + k;
        uint4 v = w4[(size_t)p * (NBINS / 4) + row4 + q];
        sx += v.x; sy += v.y; sz += v.z; sw += v.w;
    }
    atomicAdd(&sums[q * 4 + 0], sx);
    atomicAdd(&sums[q * 4 + 1], sy);
    atomicAdd(&sums[q * 4 + 2], sz);
    atomicAdd(&sums[q * 4 + 3], sw);
    __syncthreads();

    if (threadIdx.x < NUM_CLASSES) {
        float v = (blockIdx.x == 0) ? 0.0f : (float)sums[threadIdx.x];
        out[blockIdx.x * NUM_CLASSES + threadIdx.x] = v;
    }
}

extern "C" void kernel_launch(void* const* d_in, const int* in_sizes, int n_in,
                              void* d_out, int out_size, void* d_ws, size_t ws_size,
                              hipStream_t stream) {
    const int* y_true = (const int*)d_in[0];
    const int* y_pred = (const int*)d_in[1];
    float* out = (float*)d_out;
    unsigned int* ws = (unsigned int*)d_ws;    // needs GRID1*NBINS*4 = 8 MB
    int n = in_sizes[0];

    confmat_partial<<<GRID1, BLOCK, 0, stream>>>(y_true, y_pred, ws, n);
    confmat_reduce<<<GRID2, BLOCK, 0, stream>>>(ws, out);
}